// Round 1
// baseline (961.015 us; speedup 1.0000x reference)
//
#include <hip/hip_runtime.h>

#define LN    8192
#define VPADF 8464   // 8192 + 272 zero pad (covers t+k+7 overrun per-wave bounds)
#define NPOOL 1024

__global__ __launch_bounds__(512)
void acf_mlp_kernel(const float* __restrict__ x,
                    const float* __restrict__ W1, const float* __restrict__ b1,
                    const float* __restrict__ W2, const float* __restrict__ b2,
                    const float* __restrict__ W3, const float* __restrict__ b3,
                    float* __restrict__ out)
{
    __shared__ __align__(16) float vsh[VPADF];
    __shared__ __align__(16) float pbuf[NPOOL];
    __shared__ __align__(16) float h1[512];
    __shared__ __align__(16) float h2[256];
    __shared__ float red[8];

    const int tid  = threadIdx.x;
    const int row  = blockIdx.x;
    const int lane = tid & 63;
    const int wv   = tid >> 6;   // wave 0..7

    // ---- stage row into LDS (fp32), zero pad tail ----
    const float4* xr = reinterpret_cast<const float4*>(x + (size_t)row * LN);
    float4* v4 = reinterpret_cast<float4*>(vsh);
    for (int c = tid; c < LN / 4; c += 512) v4[c] = xr[c];
    for (int i = LN + tid; i < VPADF; i += 512) vsh[i] = 0.f;
    __syncthreads();

    // ---- ACF: 4 rounds x 8 waves x 256 lags; thread owns 4 consecutive lags ----
    const float4* vc4 = reinterpret_cast<const float4*>(vsh);
    for (int r = 0; r < 4; ++r) {
        // snake assignment balances triangular work across waves
        int sw   = (r & 1) ? (7 - wv) : wv;
        int wb   = r * 2048 + sw * 256;      // wave's base lag
        int koff = wb + 4 * lane;            // thread's base lag
        int Tw   = LN - wb;                  // triangular bound (mult of 256)
        float a0 = 0.f, a1 = 0.f, a2 = 0.f, a3 = 0.f;
        #pragma unroll 4
        for (int t = 0; t < Tw; t += 4) {
            float4 vb = vc4[t >> 2];                 // broadcast (uniform addr)
            int wq = (t + koff) >> 2;
            float4 w0 = vc4[wq];                     // lane-stride 16B: conflict-free
            float4 w1 = vc4[wq + 1];
            a0 += vb.x*w0.x; a0 += vb.y*w0.y; a0 += vb.z*w0.z; a0 += vb.w*w0.w;
            a1 += vb.x*w0.y; a1 += vb.y*w0.z; a1 += vb.z*w0.w; a1 += vb.w*w1.x;
            a2 += vb.x*w0.z; a2 += vb.y*w0.w; a2 += vb.z*w1.x; a2 += vb.w*w1.y;
            a3 += vb.x*w0.w; a3 += vb.y*w1.x; a3 += vb.z*w1.y; a3 += vb.w*w1.z;
        }
        // pool-of-8: two adjacent lanes hold one pool
        float m  = fmaxf(fmaxf(a0, a1), fmaxf(a2, a3));
        float pm = __shfl_xor(m, 1);
        if ((lane & 1) == 0)
            pbuf[(wb >> 3) + (lane >> 1)] = fmaxf(m, pm);
    }
    __syncthreads();

    // ---- row max + normalize ----
    float p0 = pbuf[2 * tid], p1 = pbuf[2 * tid + 1];
    float mx = fmaxf(p0, p1);
    for (int off = 32; off > 0; off >>= 1) mx = fmaxf(mx, __shfl_xor(mx, off));
    if (lane == 0) red[wv] = mx;
    __syncthreads();
    float pmax = red[0];
    #pragma unroll
    for (int i = 1; i < 8; ++i) pmax = fmaxf(pmax, red[i]);
    float inv = 1.0f / pmax;
    pbuf[2 * tid]     = p0 * inv;
    pbuf[2 * tid + 1] = p1 * inv;
    __syncthreads();

    // ---- layer 1: 512 neurons, K=1024 ----
    {
        const float4* n4 = reinterpret_cast<const float4*>(pbuf);
        const float4* w4 = reinterpret_cast<const float4*>(W1 + (size_t)tid * 1024);
        float acc = 0.f;
        #pragma unroll 4
        for (int c = 0; c < 256; ++c) {
            float4 nv = n4[c], wt = w4[c];
            acc += nv.x*wt.x + nv.y*wt.y + nv.z*wt.z + nv.w*wt.w;
        }
        acc += b1[tid];
        h1[tid] = (acc > 0.f) ? acc : 0.01f * acc;
    }
    __syncthreads();

    // ---- layer 2: 256 neurons, K=512 ----
    if (tid < 256) {
        const float4* n4 = reinterpret_cast<const float4*>(h1);
        const float4* w4 = reinterpret_cast<const float4*>(W2 + (size_t)tid * 512);
        float acc = 0.f;
        #pragma unroll 4
        for (int c = 0; c < 128; ++c) {
            float4 nv = n4[c], wt = w4[c];
            acc += nv.x*wt.x + nv.y*wt.y + nv.z*wt.z + nv.w*wt.w;
        }
        acc += b2[tid];
        h2[tid] = (acc > 0.f) ? acc : 0.01f * acc;
    }
    __syncthreads();

    // ---- layer 3: 4 outputs, K=256 (wave 0 only) ----
    if (tid < 64) {
        int o = tid & 3, seg = tid >> 2;
        float acc = 0.f;
        #pragma unroll
        for (int m = 0; m < 16; ++m) {
            int k = seg * 16 + m;
            acc += h2[k] * W3[o * 256 + k];
        }
        for (int off = 4; off < 64; off <<= 1) acc += __shfl_xor(acc, off);
        if (tid < 4) out[row * 4 + o] = acc + b3[o];
    }
}

extern "C" void kernel_launch(void* const* d_in, const int* in_sizes, int n_in,
                              void* d_out, int out_size, void* d_ws, size_t ws_size,
                              hipStream_t stream)
{
    const float* x  = (const float*)d_in[0];
    const float* W1 = (const float*)d_in[1];
    const float* b1 = (const float*)d_in[2];
    const float* W2 = (const float*)d_in[3];
    const float* b2 = (const float*)d_in[4];
    const float* W3 = (const float*)d_in[5];
    const float* b3 = (const float*)d_in[6];
    float* outp = (float*)d_out;

    hipLaunchKernelGGL(acf_mlp_kernel, dim3(256), dim3(512), 0, stream,
                       x, W1, b1, W2, b2, W3, b3, outp);
}

// Round 2
// 333.644 us; speedup vs baseline: 2.8804x; 2.8804x over previous
//
#include <hip/hip_runtime.h>

#define LN    8192
#define VQ    2176      // 8704 floats (512-float zero pad) as float4 quads
#define NPOOL 1024

// XOR bank swizzle on quad index: spreads lane-stride-2-quad reads across all banks
__device__ __forceinline__ int swz(int q) { return q ^ ((q >> 3) & 7); }

__global__ __launch_bounds__(512)
void acf_mlp_kernel(const float* __restrict__ x,
                    const float* __restrict__ W1, const float* __restrict__ b1,
                    const float* __restrict__ W2, const float* __restrict__ b2,
                    const float* __restrict__ W3, const float* __restrict__ b3,
                    float* __restrict__ out)
{
    __shared__ __align__(16) float4 vsh[VQ];
    __shared__ __align__(16) float pbuf[NPOOL];
    __shared__ __align__(16) float h1[512];
    __shared__ __align__(16) float h2[256];
    __shared__ float red[8];

    const int tid  = threadIdx.x;
    const int row  = blockIdx.x;
    const int lane = tid & 63;
    const int wv   = tid >> 6;   // wave 0..7

    // ---- stage row into LDS (swizzled), zero pad tail ----
    const float4* xr = reinterpret_cast<const float4*>(x + (size_t)row * LN);
    for (int c = tid; c < LN / 4; c += 512) vsh[swz(c)] = xr[c];
    if (tid < VQ - LN / 4) vsh[swz(LN / 4 + tid)] = make_float4(0.f, 0.f, 0.f, 0.f);
    __syncthreads();

    // ---- ACF: 16 regions x 512 lags; wave w does regions w and 15-w (equal work).
    //      Thread owns 8 consecutive lags; tile = 8 lags x 32 t = 256 FMA per 18 LDS reads.
    for (int half = 0; half < 2; ++half) {
        const int r   = half ? (15 - wv) : wv;
        const int k0q = 128 * r + 2 * lane;        // (lag base)/4 in quads
        const int Tr  = LN - 512 * r;              // t-bound (mult of 512)
        float a0 = 0.f, a1 = 0.f, a2 = 0.f, a3 = 0.f;
        float a4 = 0.f, a5 = 0.f, a6 = 0.f, a7 = 0.f;
        float* a[8] = {&a0, &a1, &a2, &a3, &a4, &a5, &a6, &a7};

        for (int t = 0; t < Tr; t += 32) {
            const int qt = t >> 2;                 // mult of 8
            float4 vb[8];
            #pragma unroll
            for (int m = 0; m < 8; ++m) vb[m] = vsh[swz(qt + m)];
            const float* vbf = reinterpret_cast<const float*>(vb);
            const int qw = qt + k0q;
            #pragma unroll
            for (int m = 0; m < 10; ++m) {
                const float4 wq = vsh[swz(qw + m)];
                const float wf[4] = {wq.x, wq.y, wq.z, wq.w};
                #pragma unroll
                for (int e = 0; e < 4; ++e) {
                    const int c = 4 * m + e;       // window offset 0..39
                    #pragma unroll
                    for (int j = 0; j < 8; ++j) {
                        const int tt = c - j;
                        if (tt >= 0 && tt < 32)
                            *a[j] = fmaf(vbf[tt], wf[e], *a[j]);
                    }
                }
            }
        }
        // pool-of-8 is thread-local now
        float m01 = fmaxf(a0, a1), m23 = fmaxf(a2, a3);
        float m45 = fmaxf(a4, a5), m67 = fmaxf(a6, a7);
        pbuf[64 * r + lane] = fmaxf(fmaxf(m01, m23), fmaxf(m45, m67));
    }
    __syncthreads();

    // ---- row max + normalize ----
    float p0 = pbuf[2 * tid], p1 = pbuf[2 * tid + 1];
    float mx = fmaxf(p0, p1);
    for (int off = 32; off > 0; off >>= 1) mx = fmaxf(mx, __shfl_xor(mx, off));
    if (lane == 0) red[wv] = mx;
    __syncthreads();
    float pmax = red[0];
    #pragma unroll
    for (int i = 1; i < 8; ++i) pmax = fmaxf(pmax, red[i]);
    float inv = 1.0f / pmax;
    pbuf[2 * tid]     = p0 * inv;
    pbuf[2 * tid + 1] = p1 * inv;
    __syncthreads();

    // ---- layer 1: 512 neurons, K=1024 ----
    {
        const float4* n4 = reinterpret_cast<const float4*>(pbuf);
        const float4* w4 = reinterpret_cast<const float4*>(W1 + (size_t)tid * 1024);
        float acc = 0.f;
        #pragma unroll 4
        for (int c = 0; c < 256; ++c) {
            float4 nv = n4[c], wt = w4[c];
            acc += nv.x*wt.x + nv.y*wt.y + nv.z*wt.z + nv.w*wt.w;
        }
        acc += b1[tid];
        h1[tid] = (acc > 0.f) ? acc : 0.01f * acc;
    }
    __syncthreads();

    // ---- layer 2: 256 neurons, K=512 ----
    if (tid < 256) {
        const float4* n4 = reinterpret_cast<const float4*>(h1);
        const float4* w4 = reinterpret_cast<const float4*>(W2 + (size_t)tid * 512);
        float acc = 0.f;
        #pragma unroll 4
        for (int c = 0; c < 128; ++c) {
            float4 nv = n4[c], wt = w4[c];
            acc += nv.x*wt.x + nv.y*wt.y + nv.z*wt.z + nv.w*wt.w;
        }
        acc += b2[tid];
        h2[tid] = (acc > 0.f) ? acc : 0.01f * acc;
    }
    __syncthreads();

    // ---- layer 3: 4 outputs, K=256 (wave 0 only) ----
    if (tid < 64) {
        int o = tid & 3, seg = tid >> 2;
        float acc = 0.f;
        #pragma unroll
        for (int m = 0; m < 16; ++m) {
            int k = seg * 16 + m;
            acc += h2[k] * W3[o * 256 + k];
        }
        for (int off = 4; off < 64; off <<= 1) acc += __shfl_xor(acc, off);
        if (tid < 4) out[row * 4 + o] = acc + b3[o];
    }
}

extern "C" void kernel_launch(void* const* d_in, const int* in_sizes, int n_in,
                              void* d_out, int out_size, void* d_ws, size_t ws_size,
                              hipStream_t stream)
{
    const float* x  = (const float*)d_in[0];
    const float* W1 = (const float*)d_in[1];
    const float* b1 = (const float*)d_in[2];
    const float* W2 = (const float*)d_in[3];
    const float* b2 = (const float*)d_in[4];
    const float* W3 = (const float*)d_in[5];
    const float* b3 = (const float*)d_in[6];
    float* outp = (float*)d_out;

    hipLaunchKernelGGL(acf_mlp_kernel, dim3(256), dim3(512), 0, stream,
                       x, W1, b1, W2, b2, W3, b3, outp);
}

// Round 3
// 165.842 us; speedup vs baseline: 5.7948x; 2.0118x over previous
//
#include <hip/hip_runtime.h>

typedef __attribute__((ext_vector_type(4))) short bf16x4;
typedef __attribute__((ext_vector_type(4))) float f32x4;

#define LN 8192
#define SA_ROWB 4176          // bytes per shifted-copy row (2088 bf16 elems)
#define SB_BYTES 17408        // 1088 x 16B slots (parity-split layout)

__device__ __forceinline__ unsigned short f2bf(float f) {
    unsigned int u = __float_as_uint(f);
    u += 0x7fffu + ((u >> 16) & 1u);
    return (unsigned short)(u >> 16);
}
__device__ __forceinline__ float lrelu(float v) { return v > 0.f ? v : 0.01f * v; }

#define MFMA(a, b, c) __builtin_amdgcn_mfma_f32_16x16x16bf16_1k((a), (b), (c), 0, 0, 0)

// K1: per row: ACF via bf16 MFMA -> pool8 -> row-max normalize -> ws
__global__ __launch_bounds__(512)
void acf_kernel(const float* __restrict__ x, float* __restrict__ ws)
{
    __shared__ __align__(16) unsigned char sbB[SB_BYTES];
    __shared__ __align__(16) unsigned char sa[8 * SA_ROWB + 16];
    __shared__ float pbuf[1024];
    __shared__ float red[8];

    const int tid  = threadIdx.x;
    const int row  = blockIdx.x;
    const int lane = tid & 63;
    const int wv   = tid >> 6;
    const float* xr = x + (size_t)row * LN;

    // ---- build S_B: bf16 v, parity-split by 16B-quad (even quads | odd quads) ----
    for (int idx = tid; idx < 2176; idx += 512) {
        int E4 = idx << 2;
        float4 v = make_float4(0.f, 0.f, 0.f, 0.f);
        if (E4 < LN) v = *(const float4*)(xr + E4);
        unsigned long long pk = (unsigned long long)f2bf(v.x)
                              | ((unsigned long long)f2bf(v.y) << 16)
                              | ((unsigned long long)f2bf(v.z) << 32)
                              | ((unsigned long long)f2bf(v.w) << 48);
        int q = idx >> 1, p = q & 1, r = idx >> 2, hf = idx & 1;
        *(unsigned long long*)(sbB + 16 * (r + 544 * p) + 8 * hf) = pk;
    }

    // ---- lane constants ----
    const int g   = lane >> 4;        // 16-lane group 0..3 (k-block)
    const int j   = lane & 15;        // B col / A row index
    const int dcp = lane & 7;         // which shifted copy (i & 7)
    const int hh  = (lane >> 3) & 1;  // i >> 3
    // A: byte offset inside chunk-copy region; add 64*(mq - 64*ch) per iter
    const int abase = dcp * SA_ROWB + (dcp & 1) * 8 + 2 * (16 - 8 * hh + 4 * g);
    // B: lane-const part; add 32*mq + 256*blk per read
    const int bbase = 16 * (j + 544 * (g >> 1)) + 8 * (g & 1);

    const int blk1 = 2 * wv;          // + blk1+1
    const int blk3 = 30 - 2 * wv;     // + blk3+1
    const int b1 = 256 - 8 * blk1;
    const int b2 = b1 - 8;
    const int b3 = 256 - 8 * blk3;
    const int b4 = b3 - 8;

    f32x4 acc1 = {0.f,0.f,0.f,0.f};
    f32x4 acc2 = acc1, acc3 = acc1, acc4 = acc1;

    for (int ch = 0; ch < 4; ++ch) {
        const int tc = ch << 11;      // 2048*ch
        __syncthreads();              // previous chunk readers done
        // ---- build 8 shifted bf16 copies: S_d[p] = v[tc + p - 16 - d] ----
        for (int d = 0; d < 8; ++d) {
            unsigned char* cb = sa + d * SA_ROWB + (d & 1) * 8;
            for (int p4 = tid << 2; p4 < 2088; p4 += 2048) {
                int s = tc + p4 - 16 - d;
                unsigned long long pk = 0;
                #pragma unroll
                for (int e = 0; e < 4; ++e) {
                    int se = s + e;
                    float f = (se >= 0 && se < LN) ? xr[se] : 0.f;
                    pk |= (unsigned long long)f2bf(f) << (16 * e);
                }
                *(unsigned long long*)(cb + 2 * p4) = pk;
            }
        }
        __syncthreads();

        const unsigned char* ap  = sa + abase;
        const unsigned char* bp1 = sbB + bbase + 256 * blk1;
        const unsigned char* bp2 = sbB + bbase + 256 * blk3;
        const int mq_end = ch * 64 + 64;
        for (int mq = ch * 64; mq < mq_end; ++mq) {
            if (mq < b1) {
                const unsigned char* a = ap + ((mq - ch * 64) << 6);
                bf16x4 A1 = *(const bf16x4*)(a);
                bf16x4 A2 = *(const bf16x4*)(a + 32);
                const unsigned char* bq1 = bp1 + (mq << 5);
                {
                    bf16x4 B11 = *(const bf16x4*)(bq1);
                    bf16x4 B12 = *(const bf16x4*)(bq1 + 16);
                    acc1 = MFMA(A1, B11, acc1);
                    acc1 = MFMA(A2, B12, acc1);
                }
                if (mq < b2) {
                    bf16x4 B21 = *(const bf16x4*)(bq1 + 256);
                    bf16x4 B22 = *(const bf16x4*)(bq1 + 272);
                    acc2 = MFMA(A1, B21, acc2);
                    acc2 = MFMA(A2, B22, acc2);
                }
                if (mq < b3) {
                    const unsigned char* bq2 = bp2 + (mq << 5);
                    bf16x4 B31 = *(const bf16x4*)(bq2);
                    bf16x4 B32 = *(const bf16x4*)(bq2 + 16);
                    acc3 = MFMA(A1, B31, acc3);
                    acc3 = MFMA(A2, B32, acc3);
                    if (mq < b4) {
                        bf16x4 B41 = *(const bf16x4*)(bq2 + 256);
                        bf16x4 B42 = *(const bf16x4*)(bq2 + 272);
                        acc4 = MFMA(A1, B41, acc4);
                        acc4 = MFMA(A2, B42, acc4);
                    }
                }
            }
        }
    }

    // ---- pool-of-8: lag = 256*blk + 16*j + 4*g + r ----
    {
        float m1 = fmaxf(fmaxf(acc1[0], acc1[1]), fmaxf(acc1[2], acc1[3]));
        float m2 = fmaxf(fmaxf(acc2[0], acc2[1]), fmaxf(acc2[2], acc2[3]));
        float m3 = fmaxf(fmaxf(acc3[0], acc3[1]), fmaxf(acc3[2], acc3[3]));
        float m4 = fmaxf(fmaxf(acc4[0], acc4[1]), fmaxf(acc4[2], acc4[3]));
        float o1 = __shfl_xor(m1, 16);
        float o2 = __shfl_xor(m2, 16);
        float o3 = __shfl_xor(m3, 16);
        float o4 = __shfl_xor(m4, 16);
        if (!(g & 1)) {
            int pi = 2 * j + (g >> 1);
            pbuf[32 * blk1 + pi]       = fmaxf(m1, o1);
            pbuf[32 * (blk1 + 1) + pi] = fmaxf(m2, o2);
            pbuf[32 * blk3 + pi]       = fmaxf(m3, o3);
            pbuf[32 * (blk3 + 1) + pi] = fmaxf(m4, o4);
        }
    }
    __syncthreads();

    // ---- row max + normalize -> ws ----
    float p0 = pbuf[2 * tid], p1 = pbuf[2 * tid + 1];
    float mx = fmaxf(p0, p1);
    for (int off = 32; off > 0; off >>= 1) mx = fmaxf(mx, __shfl_xor(mx, off));
    if (lane == 0) red[wv] = mx;
    __syncthreads();
    float pmax = red[0];
    #pragma unroll
    for (int k = 1; k < 8; ++k) pmax = fmaxf(pmax, red[k]);
    float inv = 1.0f / pmax;
    float* wr = ws + (size_t)row * 1024;
    wr[2 * tid]     = p0 * inv;
    wr[2 * tid + 1] = p1 * inv;
}

// K2: MLP over all rows; 64 blocks x 4 rows -> weight L2 traffic /4
__global__ __launch_bounds__(512)
void mlp_kernel(const float* __restrict__ ws,
                const float* __restrict__ W1, const float* __restrict__ b1,
                const float* __restrict__ W2, const float* __restrict__ b2,
                const float* __restrict__ W3, const float* __restrict__ b3,
                float* __restrict__ out)
{
    __shared__ float h1s[4][512];
    __shared__ float h2s[4][256];
    const int tid = threadIdx.x;
    const int rb  = blockIdx.x * 4;

    // layer 1: neuron = tid, 4 rows; norm rows read wave-uniform (scalarizable)
    {
        const float4* w4 = (const float4*)(W1 + (size_t)tid * 1024);
        const float4* n0 = (const float4*)(ws + (size_t)rb * 1024);
        float a0 = 0.f, a1 = 0.f, a2 = 0.f, a3 = 0.f;
        for (int c = 0; c < 256; ++c) {
            float4 w  = w4[c];
            float4 v0 = n0[c], v1 = n0[c + 256], v2 = n0[c + 512], v3 = n0[c + 768];
            a0 += w.x*v0.x + w.y*v0.y + w.z*v0.z + w.w*v0.w;
            a1 += w.x*v1.x + w.y*v1.y + w.z*v1.z + w.w*v1.w;
            a2 += w.x*v2.x + w.y*v2.y + w.z*v2.z + w.w*v2.w;
            a3 += w.x*v3.x + w.y*v3.y + w.z*v3.z + w.w*v3.w;
        }
        float bb = b1[tid];
        h1s[0][tid] = lrelu(a0 + bb);
        h1s[1][tid] = lrelu(a1 + bb);
        h1s[2][tid] = lrelu(a2 + bb);
        h1s[3][tid] = lrelu(a3 + bb);
    }
    __syncthreads();

    // layer 2: neuron = tid&255, two rows each
    {
        int n = tid & 255, r0 = (tid >> 8) << 1;
        const float4* w4 = (const float4*)(W2 + (size_t)n * 512);
        float a0 = 0.f, a1 = 0.f;
        for (int c = 0; c < 128; ++c) {
            float4 w  = w4[c];
            float4 v0 = *(const float4*)(&h1s[r0][4 * c]);
            float4 v1 = *(const float4*)(&h1s[r0 + 1][4 * c]);
            a0 += w.x*v0.x + w.y*v0.y + w.z*v0.z + w.w*v0.w;
            a1 += w.x*v1.x + w.y*v1.y + w.z*v1.z + w.w*v1.w;
        }
        float bb = b2[n];
        h2s[r0][n]     = lrelu(a0 + bb);
        h2s[r0 + 1][n] = lrelu(a1 + bb);
    }
    __syncthreads();

    // layer 3: 4 outs x 4 rows, 4-seg split + shuffle reduce
    if (tid < 64) {
        int o = tid & 3, r = (tid >> 2) & 3, seg = tid >> 4;
        const float* w = W3 + o * 256;
        float a = 0.f;
        for (int k = seg * 64; k < seg * 64 + 64; ++k) a += h2s[r][k] * w[k];
        a += __shfl_xor(a, 16);
        a += __shfl_xor(a, 32);
        if (seg == 0) out[(rb + r) * 4 + o] = a + b3[o];
    }
}

extern "C" void kernel_launch(void* const* d_in, const int* in_sizes, int n_in,
                              void* d_out, int out_size, void* d_ws, size_t ws_size,
                              hipStream_t stream)
{
    const float* x  = (const float*)d_in[0];
    const float* W1 = (const float*)d_in[1];
    const float* b1 = (const float*)d_in[2];
    const float* W2 = (const float*)d_in[3];
    const float* b2 = (const float*)d_in[4];
    const float* W3 = (const float*)d_in[5];
    const float* b3 = (const float*)d_in[6];
    float* outp = (float*)d_out;
    float* wsn  = (float*)d_ws;   // 256*1024 fp32 normalized features

    hipLaunchKernelGGL(acf_kernel, dim3(256), dim3(512), 0, stream, x, wsn);
    hipLaunchKernelGGL(mlp_kernel, dim3(64), dim3(512), 0, stream,
                       wsn, W1, b1, W2, b2, W3, b3, outp);
}

// Round 4
// 150.770 us; speedup vs baseline: 6.3740x; 1.1000x over previous
//
#include <hip/hip_runtime.h>

typedef __attribute__((ext_vector_type(4))) short bf16x4;
typedef __attribute__((ext_vector_type(4))) float f32x4;

#define LN 8192
#define SA_ROWB 4176          // bytes per shifted-copy row (2088 bf16 elems)
#define SB_BYTES 17408        // 1088 x 16B slots (parity-split layout)

__device__ __forceinline__ unsigned short f2bf(float f) {
    unsigned int u = __float_as_uint(f);
    u += 0x7fffu + ((u >> 16) & 1u);
    return (unsigned short)(u >> 16);
}
__device__ __forceinline__ float lrelu(float v) { return v > 0.f ? v : 0.01f * v; }

#define MFMA(a, b, c) __builtin_amdgcn_mfma_f32_16x16x16bf16_1k((a), (b), (c), 0, 0, 0)

// K1: per row: ACF via bf16 MFMA -> pool8 -> row-max normalize -> ws
// (verified round 3 — unchanged)
__global__ __launch_bounds__(512)
void acf_kernel(const float* __restrict__ x, float* __restrict__ ws)
{
    __shared__ __align__(16) unsigned char sbB[SB_BYTES];
    __shared__ __align__(16) unsigned char sa[8 * SA_ROWB + 16];
    __shared__ float pbuf[1024];
    __shared__ float red[8];

    const int tid  = threadIdx.x;
    const int row  = blockIdx.x;
    const int lane = tid & 63;
    const int wv   = tid >> 6;
    const float* xr = x + (size_t)row * LN;

    // ---- build S_B: bf16 v, parity-split by 16B-quad (even quads | odd quads) ----
    for (int idx = tid; idx < 2176; idx += 512) {
        int E4 = idx << 2;
        float4 v = make_float4(0.f, 0.f, 0.f, 0.f);
        if (E4 < LN) v = *(const float4*)(xr + E4);
        unsigned long long pk = (unsigned long long)f2bf(v.x)
                              | ((unsigned long long)f2bf(v.y) << 16)
                              | ((unsigned long long)f2bf(v.z) << 32)
                              | ((unsigned long long)f2bf(v.w) << 48);
        int q = idx >> 1, p = q & 1, r = idx >> 2, hf = idx & 1;
        *(unsigned long long*)(sbB + 16 * (r + 544 * p) + 8 * hf) = pk;
    }

    // ---- lane constants ----
    const int g   = lane >> 4;        // 16-lane group 0..3 (k-block)
    const int j   = lane & 15;        // B col / A row index
    const int dcp = lane & 7;         // which shifted copy (i & 7)
    const int hh  = (lane >> 3) & 1;  // i >> 3
    const int abase = dcp * SA_ROWB + (dcp & 1) * 8 + 2 * (16 - 8 * hh + 4 * g);
    const int bbase = 16 * (j + 544 * (g >> 1)) + 8 * (g & 1);

    const int blk1 = 2 * wv;          // + blk1+1
    const int blk3 = 30 - 2 * wv;     // + blk3+1
    const int b1 = 256 - 8 * blk1;
    const int b2 = b1 - 8;
    const int b3 = 256 - 8 * blk3;
    const int b4 = b3 - 8;

    f32x4 acc1 = {0.f,0.f,0.f,0.f};
    f32x4 acc2 = acc1, acc3 = acc1, acc4 = acc1;

    for (int ch = 0; ch < 4; ++ch) {
        const int tc = ch << 11;      // 2048*ch
        __syncthreads();              // previous chunk readers done
        // ---- build 8 shifted bf16 copies: S_d[p] = v[tc + p - 16 - d] ----
        for (int d = 0; d < 8; ++d) {
            unsigned char* cb = sa + d * SA_ROWB + (d & 1) * 8;
            for (int p4 = tid << 2; p4 < 2088; p4 += 2048) {
                int s = tc + p4 - 16 - d;
                unsigned long long pk = 0;
                #pragma unroll
                for (int e = 0; e < 4; ++e) {
                    int se = s + e;
                    float f = (se >= 0 && se < LN) ? xr[se] : 0.f;
                    pk |= (unsigned long long)f2bf(f) << (16 * e);
                }
                *(unsigned long long*)(cb + 2 * p4) = pk;
            }
        }
        __syncthreads();

        const unsigned char* ap  = sa + abase;
        const unsigned char* bp1 = sbB + bbase + 256 * blk1;
        const unsigned char* bp2 = sbB + bbase + 256 * blk3;
        const int mq_end = ch * 64 + 64;
        for (int mq = ch * 64; mq < mq_end; ++mq) {
            if (mq < b1) {
                const unsigned char* a = ap + ((mq - ch * 64) << 6);
                bf16x4 A1 = *(const bf16x4*)(a);
                bf16x4 A2 = *(const bf16x4*)(a + 32);
                const unsigned char* bq1 = bp1 + (mq << 5);
                {
                    bf16x4 B11 = *(const bf16x4*)(bq1);
                    bf16x4 B12 = *(const bf16x4*)(bq1 + 16);
                    acc1 = MFMA(A1, B11, acc1);
                    acc1 = MFMA(A2, B12, acc1);
                }
                if (mq < b2) {
                    bf16x4 B21 = *(const bf16x4*)(bq1 + 256);
                    bf16x4 B22 = *(const bf16x4*)(bq1 + 272);
                    acc2 = MFMA(A1, B21, acc2);
                    acc2 = MFMA(A2, B22, acc2);
                }
                if (mq < b3) {
                    const unsigned char* bq2 = bp2 + (mq << 5);
                    bf16x4 B31 = *(const bf16x4*)(bq2);
                    bf16x4 B32 = *(const bf16x4*)(bq2 + 16);
                    acc3 = MFMA(A1, B31, acc3);
                    acc3 = MFMA(A2, B32, acc3);
                    if (mq < b4) {
                        bf16x4 B41 = *(const bf16x4*)(bq2 + 256);
                        bf16x4 B42 = *(const bf16x4*)(bq2 + 272);
                        acc4 = MFMA(A1, B41, acc4);
                        acc4 = MFMA(A2, B42, acc4);
                    }
                }
            }
        }
    }

    // ---- pool-of-8: lag = 256*blk + 16*j + 4*g + r ----
    {
        float m1 = fmaxf(fmaxf(acc1[0], acc1[1]), fmaxf(acc1[2], acc1[3]));
        float m2 = fmaxf(fmaxf(acc2[0], acc2[1]), fmaxf(acc2[2], acc2[3]));
        float m3 = fmaxf(fmaxf(acc3[0], acc3[1]), fmaxf(acc3[2], acc3[3]));
        float m4 = fmaxf(fmaxf(acc4[0], acc4[1]), fmaxf(acc4[2], acc4[3]));
        float o1 = __shfl_xor(m1, 16);
        float o2 = __shfl_xor(m2, 16);
        float o3 = __shfl_xor(m3, 16);
        float o4 = __shfl_xor(m4, 16);
        if (!(g & 1)) {
            int pi = 2 * j + (g >> 1);
            pbuf[32 * blk1 + pi]       = fmaxf(m1, o1);
            pbuf[32 * (blk1 + 1) + pi] = fmaxf(m2, o2);
            pbuf[32 * blk3 + pi]       = fmaxf(m3, o3);
            pbuf[32 * (blk3 + 1) + pi] = fmaxf(m4, o4);
        }
    }
    __syncthreads();

    // ---- row max + normalize -> ws ----
    float p0 = pbuf[2 * tid], p1 = pbuf[2 * tid + 1];
    float mx = fmaxf(p0, p1);
    for (int off = 32; off > 0; off >>= 1) mx = fmaxf(mx, __shfl_xor(mx, off));
    if (lane == 0) red[wv] = mx;
    __syncthreads();
    float pmax = red[0];
    #pragma unroll
    for (int k = 1; k < 8; ++k) pmax = fmaxf(pmax, red[k]);
    float inv = 1.0f / pmax;
    float* wr = ws + (size_t)row * 1024;
    wr[2 * tid]     = p0 * inv;
    wr[2 * tid + 1] = p1 * inv;
}

// K2: MLP, one row per block (256 blocks) — max parallelism, weights L2-resident
__global__ __launch_bounds__(512)
void mlp_kernel(const float* __restrict__ ws,
                const float* __restrict__ W1, const float* __restrict__ b1,
                const float* __restrict__ W2, const float* __restrict__ b2,
                const float* __restrict__ W3, const float* __restrict__ b3,
                float* __restrict__ out)
{
    __shared__ __align__(16) float nrow[1024];
    __shared__ __align__(16) float h1[512];
    __shared__ __align__(16) float p2[2][256];
    __shared__ __align__(16) float h2[256];
    const int tid = threadIdx.x;
    const int row = blockIdx.x;

    // stage normalized row (coalesced)
    if (tid < 256) {
        ((float4*)nrow)[tid] = ((const float4*)(ws + (size_t)row * 1024))[tid];
    }
    __syncthreads();

    // layer 1: neuron = tid, K=1024; nrow broadcast from LDS, W1 streamed
    {
        const float4* w4 = (const float4*)(W1 + (size_t)tid * 1024);
        const float4* n4 = (const float4*)nrow;
        float acc = 0.f;
        #pragma unroll 8
        for (int c = 0; c < 256; ++c) {
            float4 w = w4[c], n = n4[c];
            acc += w.x*n.x + w.y*n.y + w.z*n.z + w.w*n.w;
        }
        h1[tid] = lrelu(acc + b1[tid]);
    }
    __syncthreads();

    // layer 2: neuron = tid&255, split-K halves, LDS partial reduce
    {
        int n = tid & 255, h = tid >> 8;
        const float4* w4 = (const float4*)(W2 + (size_t)n * 512 + h * 256);
        const float4* a4 = (const float4*)(h1 + h * 256);
        float acc = 0.f;
        #pragma unroll 8
        for (int c = 0; c < 64; ++c) {
            float4 w = w4[c], a = a4[c];
            acc += w.x*a.x + w.y*a.y + w.z*a.z + w.w*a.w;
        }
        p2[h][n] = acc;
    }
    __syncthreads();
    if (tid < 256) h2[tid] = lrelu(p2[0][tid] + p2[1][tid] + b2[tid]);
    __syncthreads();

    // layer 3: 4 outs, K=256; 16 segs x 16 k + shuffle reduce
    if (tid < 64) {
        int o = tid & 3, seg = tid >> 2;
        const float* w = W3 + o * 256;
        float a = 0.f;
        #pragma unroll
        for (int k = seg * 16; k < seg * 16 + 16; ++k) a += h2[k] * w[k];
        for (int off = 4; off < 64; off <<= 1) a += __shfl_xor(a, off);
        if (tid < 4) out[row * 4 + o] = a + b3[o];
    }
}

extern "C" void kernel_launch(void* const* d_in, const int* in_sizes, int n_in,
                              void* d_out, int out_size, void* d_ws, size_t ws_size,
                              hipStream_t stream)
{
    const float* x  = (const float*)d_in[0];
    const float* W1 = (const float*)d_in[1];
    const float* b1 = (const float*)d_in[2];
    const float* W2 = (const float*)d_in[3];
    const float* b2 = (const float*)d_in[4];
    const float* W3 = (const float*)d_in[5];
    const float* b3 = (const float*)d_in[6];
    float* outp = (float*)d_out;
    float* wsn  = (float*)d_ws;   // 256*1024 fp32 normalized features

    hipLaunchKernelGGL(acf_kernel, dim3(256), dim3(512), 0, stream, x, wsn);
    hipLaunchKernelGGL(mlp_kernel, dim3(256), dim3(512), 0, stream,
                       wsn, W1, b1, W2, b2, W3, b3, outp);
}

// Round 5
// 96.335 us; speedup vs baseline: 9.9758x; 1.5651x over previous
//
#include <hip/hip_runtime.h>

typedef __attribute__((ext_vector_type(4))) short bf16x4;
typedef __attribute__((ext_vector_type(4))) float f32x4;

#define LN 8192
#define SA_ROWB 4176          // bytes per shifted-copy row (2088 bf16 elems)
#define SB_BYTES 17408        // 1088 x 16B slots (parity-split layout)

__device__ __forceinline__ unsigned short f2bf(float f) {
    unsigned int u = __float_as_uint(f);
    u += 0x7fffu + ((u >> 16) & 1u);
    return (unsigned short)(u >> 16);
}
__device__ __forceinline__ float lrelu(float v) { return v > 0.f ? v : 0.01f * v; }

#define MFMA(a, b, c) __builtin_amdgcn_mfma_f32_16x16x16bf16_1k((a), (b), (c), 0, 0, 0)

// K1: ACF via bf16 MFMA -> pool8 -> row-max normalize -> ws
// Round-5 change: 1024 threads (16 waves = 4/SIMD) for latency hiding;
// each wave owns lag-block pair {wv, 31-wv} (264 mq each — balanced).
// MFMA math / LDS layout byte-identical to verified round-3 kernel.
__global__ __launch_bounds__(1024)
void acf_kernel(const float* __restrict__ x, float* __restrict__ ws)
{
    __shared__ __align__(16) unsigned char sbB[SB_BYTES];
    __shared__ __align__(16) unsigned char sa[8 * SA_ROWB + 16];
    __shared__ float pbuf[1024];
    __shared__ float red[16];

    const int tid  = threadIdx.x;
    const int row  = blockIdx.x;
    const int lane = tid & 63;
    const int wv   = tid >> 6;   // 0..15
    const float* xr = x + (size_t)row * LN;

    // ---- build S_B: bf16 v, parity-split by 16B-quad ----
    for (int idx = tid; idx < 2176; idx += 1024) {
        int E4 = idx << 2;
        float4 v = make_float4(0.f, 0.f, 0.f, 0.f);
        if (E4 < LN) v = *(const float4*)(xr + E4);
        unsigned long long pk = (unsigned long long)f2bf(v.x)
                              | ((unsigned long long)f2bf(v.y) << 16)
                              | ((unsigned long long)f2bf(v.z) << 32)
                              | ((unsigned long long)f2bf(v.w) << 48);
        int q = idx >> 1, p = q & 1, r = idx >> 2, hf = idx & 1;
        *(unsigned long long*)(sbB + 16 * (r + 544 * p) + 8 * hf) = pk;
    }

    // ---- lane constants (identical mapping to round 3) ----
    const int g   = lane >> 4;
    const int j   = lane & 15;
    const int dcp = lane & 7;
    const int hh  = (lane >> 3) & 1;
    const int abase = dcp * SA_ROWB + (dcp & 1) * 8 + 2 * (16 - 8 * hh + 4 * g);
    const int bbase = 16 * (j + 544 * (g >> 1)) + 8 * (g & 1);

    const int blkA = wv;              // 0..15
    const int blkB = 31 - wv;         // 16..31
    const int bA = 256 - 8 * blkA;    // mq bound for blkA
    const int bB = 256 - 8 * blkB;    // = 8 + 8*wv, always <= bA

    f32x4 acc1 = {0.f,0.f,0.f,0.f};
    f32x4 acc2 = acc1;

    for (int ch = 0; ch < 4; ++ch) {
        const int tc = ch << 11;
        __syncthreads();
        // ---- build 8 shifted bf16 copies: S_d[p] = v[tc + p - 16 - d] ----
        for (int d = 0; d < 8; ++d) {
            unsigned char* cb = sa + d * SA_ROWB + (d & 1) * 8;
            for (int p4 = tid << 2; p4 < 2088; p4 += 4096) {
                int s = tc + p4 - 16 - d;
                unsigned long long pk = 0;
                #pragma unroll
                for (int e = 0; e < 4; ++e) {
                    int se = s + e;
                    float f = (se >= 0 && se < LN) ? xr[se] : 0.f;
                    pk |= (unsigned long long)f2bf(f) << (16 * e);
                }
                *(unsigned long long*)(cb + 2 * p4) = pk;
            }
        }
        __syncthreads();

        const unsigned char* ap  = sa + abase;
        const unsigned char* bpA = sbB + bbase + 256 * blkA;
        const unsigned char* bpB = sbB + bbase + 256 * blkB;
        const int mq_end = ch * 64 + 64;
        for (int mq = ch * 64; mq < mq_end; ++mq) {
            if (mq < bA) {
                const unsigned char* a = ap + ((mq - ch * 64) << 6);
                bf16x4 A1 = *(const bf16x4*)(a);
                bf16x4 A2 = *(const bf16x4*)(a + 32);
                const unsigned char* bqA = bpA + (mq << 5);
                acc1 = MFMA(A1, *(const bf16x4*)(bqA),      acc1);
                acc1 = MFMA(A2, *(const bf16x4*)(bqA + 16), acc1);
                if (mq < bB) {
                    const unsigned char* bqB = bpB + (mq << 5);
                    acc2 = MFMA(A1, *(const bf16x4*)(bqB),      acc2);
                    acc2 = MFMA(A2, *(const bf16x4*)(bqB + 16), acc2);
                }
            }
        }
    }

    // ---- pool-of-8: lag = 256*blk + 16*j + 4*g + r ----
    {
        float m1 = fmaxf(fmaxf(acc1[0], acc1[1]), fmaxf(acc1[2], acc1[3]));
        float m2 = fmaxf(fmaxf(acc2[0], acc2[1]), fmaxf(acc2[2], acc2[3]));
        float o1 = __shfl_xor(m1, 16);
        float o2 = __shfl_xor(m2, 16);
        if (!(g & 1)) {
            int pi = 2 * j + (g >> 1);
            pbuf[32 * blkA + pi] = fmaxf(m1, o1);
            pbuf[32 * blkB + pi] = fmaxf(m2, o2);
        }
    }
    __syncthreads();

    // ---- row max + normalize -> ws ----
    float p0 = pbuf[tid];
    float mx = p0;
    for (int off = 32; off > 0; off >>= 1) mx = fmaxf(mx, __shfl_xor(mx, off));
    if (lane == 0) red[wv] = mx;
    __syncthreads();
    float pmax = red[0];
    #pragma unroll
    for (int k = 1; k < 16; ++k) pmax = fmaxf(pmax, red[k]);
    ws[(size_t)row * 1024 + tid] = p0 * (1.0f / pmax);
}

// K2: MLP, one row per block; split-K per wave => fully coalesced weight loads
__global__ __launch_bounds__(512)
void mlp_kernel(const float* __restrict__ ws,
                const float* __restrict__ W1, const float* __restrict__ b1,
                const float* __restrict__ W2, const float* __restrict__ b2,
                const float* __restrict__ W3, const float* __restrict__ b3,
                float* __restrict__ out)
{
    __shared__ __align__(16) float nrow[1024];
    __shared__ __align__(16) float h1[512];
    __shared__ __align__(16) float h2[256];
    const int tid  = threadIdx.x;
    const int lane = tid & 63;
    const int wv   = tid >> 6;
    const int row  = blockIdx.x;

    if (tid < 256)
        ((float4*)nrow)[tid] = ((const float4*)(ws + (size_t)row * 1024))[tid];
    __syncthreads();

    // ---- layer 1: wave wv owns neurons [64*wv, 64*wv+64); K=1024 split over lanes ----
    {
        const float4* n4 = (const float4*)nrow;
        for (int n0 = 0; n0 < 64; n0 += 2) {
            const int na = wv * 64 + n0;
            const float4* wa = (const float4*)(W1 + (size_t)na * 1024);
            const float4* wb = wa + 256;
            float sa = 0.f, sb = 0.f;
            #pragma unroll
            for (int q = 0; q < 4; ++q) {
                float4 nv = n4[lane + 64 * q];
                float4 w1v = wa[lane + 64 * q];
                float4 w2v = wb[lane + 64 * q];
                sa += w1v.x*nv.x + w1v.y*nv.y + w1v.z*nv.z + w1v.w*nv.w;
                sb += w2v.x*nv.x + w2v.y*nv.y + w2v.z*nv.z + w2v.w*nv.w;
            }
            for (int off = 32; off > 0; off >>= 1) {
                sa += __shfl_xor(sa, off);
                sb += __shfl_xor(sb, off);
            }
            if (lane == 0) {
                h1[na]     = lrelu(sa + b1[na]);
                h1[na + 1] = lrelu(sb + b1[na + 1]);
            }
        }
    }
    __syncthreads();

    // ---- layer 2: wave wv owns neurons [32*wv, 32*wv+32); K=512 ----
    {
        const float4* a4 = (const float4*)h1;
        for (int n0 = 0; n0 < 32; n0 += 2) {
            const int na = wv * 32 + n0;
            const float4* wa = (const float4*)(W2 + (size_t)na * 512);
            const float4* wb = wa + 128;
            float sa = 0.f, sb = 0.f;
            #pragma unroll
            for (int q = 0; q < 2; ++q) {
                float4 av = a4[lane + 64 * q];
                float4 w1v = wa[lane + 64 * q];
                float4 w2v = wb[lane + 64 * q];
                sa += w1v.x*av.x + w1v.y*av.y + w1v.z*av.z + w1v.w*av.w;
                sb += w2v.x*av.x + w2v.y*av.y + w2v.z*av.z + w2v.w*av.w;
            }
            for (int off = 32; off > 0; off >>= 1) {
                sa += __shfl_xor(sa, off);
                sb += __shfl_xor(sb, off);
            }
            if (lane == 0) {
                h2[na]     = lrelu(sa + b2[na]);
                h2[na + 1] = lrelu(sb + b2[na + 1]);
            }
        }
    }
    __syncthreads();

    // ---- layer 3: waves 0..3 each own one output; K=256 ----
    if (wv < 4) {
        const float4 w = ((const float4*)(W3 + wv * 256))[lane];
        const float4 a = ((const float4*)h2)[lane];
        float s = w.x*a.x + w.y*a.y + w.z*a.z + w.w*a.w;
        for (int off = 32; off > 0; off >>= 1) s += __shfl_xor(s, off);
        if (lane == 0) out[row * 4 + wv] = s + b3[wv];
    }
}

extern "C" void kernel_launch(void* const* d_in, const int* in_sizes, int n_in,
                              void* d_out, int out_size, void* d_ws, size_t ws_size,
                              hipStream_t stream)
{
    const float* x  = (const float*)d_in[0];
    const float* W1 = (const float*)d_in[1];
    const float* b1 = (const float*)d_in[2];
    const float* W2 = (const float*)d_in[3];
    const float* b2 = (const float*)d_in[4];
    const float* W3 = (const float*)d_in[5];
    const float* b3 = (const float*)d_in[6];
    float* outp = (float*)d_out;
    float* wsn  = (float*)d_ws;   // 256*1024 fp32 normalized features

    hipLaunchKernelGGL(acf_kernel, dim3(256), dim3(1024), 0, stream, x, wsn);
    hipLaunchKernelGGL(mlp_kernel, dim3(256), dim3(512), 0, stream,
                       wsn, W1, b1, W2, b2, W3, b3, outp);
}

// Round 6
// 92.053 us; speedup vs baseline: 10.4398x; 1.0465x over previous
//
#include <hip/hip_runtime.h>

typedef __attribute__((ext_vector_type(4))) short bf16x4;
typedef __attribute__((ext_vector_type(4))) float f32x4;

#define LN 8192
#define SA_ROWB 4176          // bytes per shifted-copy row (2088 bf16 elems)
#define SB_BYTES 17408        // 1088 x 16B slots (parity-split layout)

__device__ __forceinline__ unsigned short f2bf(float f) {
    unsigned int u = __float_as_uint(f);
    u += 0x7fffu + ((u >> 16) & 1u);
    return (unsigned short)(u >> 16);
}
__device__ __forceinline__ float lrelu(float v) { return v > 0.f ? v : 0.01f * v; }

#define MFMA(a, b, c) __builtin_amdgcn_mfma_f32_16x16x16bf16_1k((a), (b), (c), 0, 0, 0)

// K1: ACF via bf16 MFMA -> pool8 -> row-max normalize -> ws
// Round-6 change: mq-loop unrolled x4 (batched LDS loads -> batched MFMAs) for ILP.
// MFMA sequence per accumulator unchanged -> bitwise-identical math to round 5.
__global__ __launch_bounds__(1024)
void acf_kernel(const float* __restrict__ x, float* __restrict__ ws)
{
    __shared__ __align__(16) unsigned char sbB[SB_BYTES];
    __shared__ __align__(16) unsigned char sa[8 * SA_ROWB + 16];
    __shared__ float pbuf[1024];
    __shared__ float red[16];

    const int tid  = threadIdx.x;
    const int row  = blockIdx.x;
    const int lane = tid & 63;
    const int wv   = tid >> 6;   // 0..15
    const float* xr = x + (size_t)row * LN;

    // ---- build S_B: bf16 v, parity-split by 16B-quad ----
    for (int idx = tid; idx < 2176; idx += 1024) {
        int E4 = idx << 2;
        float4 v = make_float4(0.f, 0.f, 0.f, 0.f);
        if (E4 < LN) v = *(const float4*)(xr + E4);
        unsigned long long pk = (unsigned long long)f2bf(v.x)
                              | ((unsigned long long)f2bf(v.y) << 16)
                              | ((unsigned long long)f2bf(v.z) << 32)
                              | ((unsigned long long)f2bf(v.w) << 48);
        int q = idx >> 1, p = q & 1, r = idx >> 2, hf = idx & 1;
        *(unsigned long long*)(sbB + 16 * (r + 544 * p) + 8 * hf) = pk;
    }

    // ---- lane constants (identical mapping to round 3) ----
    const int g   = lane >> 4;
    const int j   = lane & 15;
    const int dcp = lane & 7;
    const int hh  = (lane >> 3) & 1;
    const int abase = dcp * SA_ROWB + (dcp & 1) * 8 + 2 * (16 - 8 * hh + 4 * g);
    const int bbase = 16 * (j + 544 * (g >> 1)) + 8 * (g & 1);

    const int blkA = wv;              // 0..15
    const int blkB = 31 - wv;         // 16..31
    const int bA = 256 - 8 * blkA;    // mq bound for blkA (mult of 8)
    const int bB = 256 - 8 * blkB;    // = 8 + 8*wv (mult of 8), always <= bA

    f32x4 acc1 = {0.f,0.f,0.f,0.f};
    f32x4 acc2 = acc1;

    for (int ch = 0; ch < 4; ++ch) {
        const int tc = ch << 11;
        __syncthreads();
        // ---- build 8 shifted bf16 copies: S_d[p] = v[tc + p - 16 - d] ----
        for (int d = 0; d < 8; ++d) {
            unsigned char* cb = sa + d * SA_ROWB + (d & 1) * 8;
            for (int p4 = tid << 2; p4 < 2088; p4 += 4096) {
                int s = tc + p4 - 16 - d;
                unsigned long long pk = 0;
                #pragma unroll
                for (int e = 0; e < 4; ++e) {
                    int se = s + e;
                    float f = (se >= 0 && se < LN) ? xr[se] : 0.f;
                    pk |= (unsigned long long)f2bf(f) << (16 * e);
                }
                *(unsigned long long*)(cb + 2 * p4) = pk;
            }
        }
        __syncthreads();

        const unsigned char* ap  = sa + abase;
        const unsigned char* bpA = sbB + bbase + 256 * blkA;
        const unsigned char* bpB = sbB + bbase + 256 * blkB;
        const int mq_end = ch * 64 + 64;
        // mq unrolled x4: bounds are mult of 8, groups of 4 never straddle ->
        // (mq < bA) uniform across the group; identical MFMA order per acc.
        for (int mq = ch * 64; mq < mq_end; mq += 4) {
            if (mq < bA) {
                const unsigned char* a = ap + ((mq - ch * 64) << 6);
                bf16x4 A1[4], A2[4], BA0[4], BA1[4];
                #pragma unroll
                for (int u = 0; u < 4; ++u) {
                    A1[u] = *(const bf16x4*)(a + 64 * u);
                    A2[u] = *(const bf16x4*)(a + 64 * u + 32);
                    const unsigned char* bqA = bpA + ((mq + u) << 5);
                    BA0[u] = *(const bf16x4*)(bqA);
                    BA1[u] = *(const bf16x4*)(bqA + 16);
                }
                if (mq < bB) {
                    bf16x4 BB0[4], BB1[4];
                    #pragma unroll
                    for (int u = 0; u < 4; ++u) {
                        const unsigned char* bqB = bpB + ((mq + u) << 5);
                        BB0[u] = *(const bf16x4*)(bqB);
                        BB1[u] = *(const bf16x4*)(bqB + 16);
                    }
                    #pragma unroll
                    for (int u = 0; u < 4; ++u) {
                        acc1 = MFMA(A1[u], BA0[u], acc1);
                        acc1 = MFMA(A2[u], BA1[u], acc1);
                        acc2 = MFMA(A1[u], BB0[u], acc2);
                        acc2 = MFMA(A2[u], BB1[u], acc2);
                    }
                } else {
                    #pragma unroll
                    for (int u = 0; u < 4; ++u) {
                        acc1 = MFMA(A1[u], BA0[u], acc1);
                        acc1 = MFMA(A2[u], BA1[u], acc1);
                    }
                }
            }
        }
    }

    // ---- pool-of-8: lag = 256*blk + 16*j + 4*g + r ----
    {
        float m1 = fmaxf(fmaxf(acc1[0], acc1[1]), fmaxf(acc1[2], acc1[3]));
        float m2 = fmaxf(fmaxf(acc2[0], acc2[1]), fmaxf(acc2[2], acc2[3]));
        float o1 = __shfl_xor(m1, 16);
        float o2 = __shfl_xor(m2, 16);
        if (!(g & 1)) {
            int pi = 2 * j + (g >> 1);
            pbuf[32 * blkA + pi] = fmaxf(m1, o1);
            pbuf[32 * blkB + pi] = fmaxf(m2, o2);
        }
    }
    __syncthreads();

    // ---- row max + normalize -> ws ----
    float p0 = pbuf[tid];
    float mx = p0;
    for (int off = 32; off > 0; off >>= 1) mx = fmaxf(mx, __shfl_xor(mx, off));
    if (lane == 0) red[wv] = mx;
    __syncthreads();
    float pmax = red[0];
    #pragma unroll
    for (int k = 1; k < 16; ++k) pmax = fmaxf(pmax, red[k]);
    ws[(size_t)row * 1024 + tid] = p0 * (1.0f / pmax);
}

// K2: MLP, one row per block; split-K per wave, 8 neurons in flight for ILP
__global__ __launch_bounds__(512)
void mlp_kernel(const float* __restrict__ ws,
                const float* __restrict__ W1, const float* __restrict__ b1,
                const float* __restrict__ W2, const float* __restrict__ b2,
                const float* __restrict__ W3, const float* __restrict__ b3,
                float* __restrict__ out)
{
    __shared__ __align__(16) float nrow[1024];
    __shared__ __align__(16) float h1[512];
    __shared__ __align__(16) float h2[256];
    const int tid  = threadIdx.x;
    const int lane = tid & 63;
    const int wv   = tid >> 6;
    const int row  = blockIdx.x;

    if (tid < 256)
        ((float4*)nrow)[tid] = ((const float4*)(ws + (size_t)row * 1024))[tid];
    __syncthreads();

    // ---- layer 1: wave wv owns neurons [64*wv, 64*wv+64), 8 in flight ----
    {
        const float4* n4 = (const float4*)nrow;
        float4 nv0 = n4[lane], nv1 = n4[lane + 64], nv2 = n4[lane + 128], nv3 = n4[lane + 192];
        for (int n0 = 0; n0 < 64; n0 += 8) {
            const int nb = wv * 64 + n0;
            float s[8];
            #pragma unroll
            for (int u = 0; u < 8; ++u) {
                const float4* wr = (const float4*)(W1 + (size_t)(nb + u) * 1024);
                float4 w0 = wr[lane], w1 = wr[lane + 64], w2 = wr[lane + 128], w3 = wr[lane + 192];
                float t0 = w0.x*nv0.x + w0.y*nv0.y + w0.z*nv0.z + w0.w*nv0.w;
                float t1 = w1.x*nv1.x + w1.y*nv1.y + w1.z*nv1.z + w1.w*nv1.w;
                float t2 = w2.x*nv2.x + w2.y*nv2.y + w2.z*nv2.z + w2.w*nv2.w;
                float t3 = w3.x*nv3.x + w3.y*nv3.y + w3.z*nv3.z + w3.w*nv3.w;
                s[u] = (t0 + t1) + (t2 + t3);
            }
            #pragma unroll
            for (int off = 32; off > 0; off >>= 1) {
                #pragma unroll
                for (int u = 0; u < 8; ++u) s[u] += __shfl_xor(s[u], off);
            }
            if (lane == 0) {
                #pragma unroll
                for (int u = 0; u < 8; ++u) h1[nb + u] = lrelu(s[u] + b1[nb + u]);
            }
        }
    }
    __syncthreads();

    // ---- layer 2: wave wv owns neurons [32*wv, 32*wv+32), 8 in flight ----
    {
        const float4* a4 = (const float4*)h1;
        float4 av0 = a4[lane], av1 = a4[lane + 64];
        for (int n0 = 0; n0 < 32; n0 += 8) {
            const int nb = wv * 32 + n0;
            float s[8];
            #pragma unroll
            for (int u = 0; u < 8; ++u) {
                const float4* wr = (const float4*)(W2 + (size_t)(nb + u) * 512);
                float4 w0 = wr[lane], w1 = wr[lane + 64];
                float t0 = w0.x*av0.x + w0.y*av0.y + w0.z*av0.z + w0.w*av0.w;
                float t1 = w1.x*av1.x + w1.y*av1.y + w1.z*av1.z + w1.w*av1.w;
                s[u] = t0 + t1;
            }
            #pragma unroll
            for (int off = 32; off > 0; off >>= 1) {
                #pragma unroll
                for (int u = 0; u < 8; ++u) s[u] += __shfl_xor(s[u], off);
            }
            if (lane == 0) {
                #pragma unroll
                for (int u = 0; u < 8; ++u) h2[nb + u] = lrelu(s[u] + b2[nb + u]);
            }
        }
    }
    __syncthreads();

    // ---- layer 3: waves 0..3 each own one output; K=256 ----
    if (wv < 4) {
        const float4 w = ((const float4*)(W3 + wv * 256))[lane];
        const float4 a = ((const float4*)h2)[lane];
        float s = w.x*a.x + w.y*a.y + w.z*a.z + w.w*a.w;
        for (int off = 32; off > 0; off >>= 1) s += __shfl_xor(s, off);
        if (lane == 0) out[row * 4 + wv] = s + b3[wv];
    }
}

extern "C" void kernel_launch(void* const* d_in, const int* in_sizes, int n_in,
                              void* d_out, int out_size, void* d_ws, size_t ws_size,
                              hipStream_t stream)
{
    const float* x  = (const float*)d_in[0];
    const float* W1 = (const float*)d_in[1];
    const float* b1 = (const float*)d_in[2];
    const float* W2 = (const float*)d_in[3];
    const float* b2 = (const float*)d_in[4];
    const float* W3 = (const float*)d_in[5];
    const float* b3 = (const float*)d_in[6];
    float* outp = (float*)d_out;
    float* wsn  = (float*)d_ws;   // 256*1024 fp32 normalized features

    hipLaunchKernelGGL(acf_kernel, dim3(256), dim3(1024), 0, stream, x, wsn);
    hipLaunchKernelGGL(mlp_kernel, dim3(256), dim3(512), 0, stream,
                       wsn, W1, b1, W2, b2, W3, b3, outp);
}

// Round 7
// 74.489 us; speedup vs baseline: 12.9015x; 1.2358x over previous
//
#include <hip/hip_runtime.h>

typedef __attribute__((ext_vector_type(8))) short bf16x8;
typedef __attribute__((ext_vector_type(16))) float f32x16;

#define LN 8192
#define SA_ROWB 4240          // bytes/shifted-copy row: 2112 bf16 + pad; 4240/16=265 ≡ 1 (mod 8) → bank spread
#define SB_OFF  33920         // B buffer starts after 8 A-rows (8*4240)
#define SMEM_BYTES 65536      // staging (52.6KB) overlaid later by 64KB partial buffer

__device__ __forceinline__ unsigned short f2bf(float f) {
    unsigned int u = __float_as_uint(f);
    u += 0x7fffu + ((u >> 16) & 1u);
    return (unsigned short)(u >> 16);
}
__device__ __forceinline__ float lrelu(float v) { return v > 0.f ? v : 0.01f * v; }
__device__ __forceinline__ float gldx(const float* p, int i) { return (i >= 0 && i < LN) ? p[i] : 0.f; }

// K1: ACF via 32x32x16 bf16 MFMA. lag = 1024*T + 32*j + i; C[i][j] = sum_tau v[tau-i]*v[tau+1024T+32j].
// A[i,k]=v[tau0+k-i] from 8 shifted LDS copies (i=8h+d -> copy d at -16h bytes);
// B[k,j]=v[tau0+1024T+32j+k] from XOR-swizzled plain bf16 copy.
// 16 waves: wave w does quarter q=w&3 of tiles T1=w>>2 and 7-T1 (146 mq each, balanced);
// quarter partials summed via 64KB LDS overlay, then pool8 -> rowmax -> normalize -> ws.
__global__ __launch_bounds__(1024)
void acf_kernel(const float* __restrict__ x, float* __restrict__ ws)
{
    __shared__ __align__(16) unsigned char smem[SMEM_BYTES];
    __shared__ float red[16];

    const int tid  = threadIdx.x;
    const int row  = blockIdx.x;
    const int lane = tid & 63;
    const int wv   = tid >> 6;
    const float* xr = x + (size_t)row * LN;

    // lane constants
    const int jj = lane & 31;         // B col / C col
    const int gp = lane >> 5;         // lane half: k-base = 8*gp
    const int dd = lane & 7;          // shift copy (i & 7)
    const int hh = (lane >> 3) & 3;   // i >> 3  (i = 8*hh + dd)
    const int aoff_lane = dd * SA_ROWB + 64 + 16 * gp - 16 * hh;

    // wave job constants: quarter q of tiles T1 and T2 (equal total work = 146 mq)
    const int q  = wv & 3;
    const int T1 = wv >> 2;
    const int T2 = 7 - T1;
    const int Q1 = 129 - 16 * T1;
    const int Q2 = 129 - 16 * T2;
    const int lo1 = q * Q1, hi1 = lo1 + Q1;
    const int lo2 = q * Q2, hi2 = lo2 + Q2;

    // ---- stage B: padded bf16 v (9248 elems), 16B-slot XOR swizzle s^((s>>3)&7) ----
    for (int s = tid; s < 1156; s += 1024) {
        const int e0 = s * 8;
        float4 fa, fb;
        if (e0 + 7 < LN) {
            fa = *(const float4*)(xr + e0);
            fb = *(const float4*)(xr + e0 + 4);
        } else {
            fa = make_float4(gldx(xr,e0),   gldx(xr,e0+1), gldx(xr,e0+2), gldx(xr,e0+3));
            fb = make_float4(gldx(xr,e0+4), gldx(xr,e0+5), gldx(xr,e0+6), gldx(xr,e0+7));
        }
        uint4 pk;
        pk.x = (unsigned)f2bf(fa.x) | ((unsigned)f2bf(fa.y) << 16);
        pk.y = (unsigned)f2bf(fa.z) | ((unsigned)f2bf(fa.w) << 16);
        pk.z = (unsigned)f2bf(fb.x) | ((unsigned)f2bf(fb.y) << 16);
        pk.w = (unsigned)f2bf(fb.z) | ((unsigned)f2bf(fb.w) << 16);
        const int ph = s ^ ((s >> 3) & 7);
        *(uint4*)(smem + SB_OFF + ph * 16) = pk;
    }

    f32x16 acc1 = {}, acc2 = {};

    for (int ch = 0; ch < 5; ++ch) {
        const int tc = ch << 11;
        __syncthreads();              // prev-chunk readers done / B staged
        // ---- stage A: copy_d[p] = v[tc + p - 32 - d], p in [0,2112); thread t owns p=4t..4t+3 ----
        if (tid < 528) {
            const int base = tc + 4 * tid - 40;
            float4 fa, fb, fc;
            if (base >= 0 && base + 11 < LN) {
                fa = *(const float4*)(xr + base);
                fb = *(const float4*)(xr + base + 4);
                fc = *(const float4*)(xr + base + 8);
            } else {
                fa = make_float4(gldx(xr,base),   gldx(xr,base+1), gldx(xr,base+2),  gldx(xr,base+3));
                fb = make_float4(gldx(xr,base+4), gldx(xr,base+5), gldx(xr,base+6),  gldx(xr,base+7));
                fc = make_float4(gldx(xr,base+8), gldx(xr,base+9), gldx(xr,base+10), gldx(xr,base+11));
            }
            unsigned short us[12];
            us[0]=f2bf(fa.x); us[1]=f2bf(fa.y); us[2]=f2bf(fa.z);  us[3]=f2bf(fa.w);
            us[4]=f2bf(fb.x); us[5]=f2bf(fb.y); us[6]=f2bf(fb.z);  us[7]=f2bf(fb.w);
            us[8]=f2bf(fc.x); us[9]=f2bf(fc.y); us[10]=f2bf(fc.z); us[11]=f2bf(fc.w);
            #pragma unroll
            for (int d = 0; d < 8; ++d) {
                unsigned long long pk = (unsigned long long)us[8-d]
                                      | ((unsigned long long)us[9-d]  << 16)
                                      | ((unsigned long long)us[10-d] << 32)
                                      | ((unsigned long long)us[11-d] << 48);
                *(unsigned long long*)(smem + d * SA_ROWB + 8 * tid) = pk;
            }
        }
        __syncthreads();

        auto job = [&](int T, int lo, int hi, f32x16& acc) {
            const int cb = ch * 128;
            int mlo = lo > cb ? lo : cb;
            int mhi = hi < cb + 128 ? hi : cb + 128;
            const unsigned char* ap = smem + aoff_lane + 32 * (mlo - cb);
            int S = 128 * T + 2 * mlo + 4 * jj + gp;
            #pragma unroll 4
            for (int mq = mlo; mq < mhi; ++mq) {
                bf16x8 A = *(const bf16x8*)ap;
                bf16x8 B = *(const bf16x8*)(smem + SB_OFF + ((S ^ ((S >> 3) & 7)) << 4));
                acc = __builtin_amdgcn_mfma_f32_32x32x16_bf16(A, B, acc, 0, 0, 0);
                ap += 32; S += 2;
            }
        };
        job(T1, lo1, hi1, acc1);
        job(T2, lo2, hi2, acc2);
    }

    __syncthreads();   // all MFMA reads done; overlay staging with partial buffer

    // partial buffer: [T][s][j(32)][i(32 f32, 16B-blocks XOR-swizzled by j&7)] = 64KB
    auto pwrite = [&](int T, int s, const f32x16& acc, bool add) {
        unsigned char* bp = smem + (T * 2 + s) * 4096 + jj * 128;
        #pragma unroll
        for (int rq = 0; rq < 4; ++rq) {
            const int bi = (2 * rq + gp) ^ (jj & 7);
            float4 w = make_float4(acc[4*rq], acc[4*rq+1], acc[4*rq+2], acc[4*rq+3]);
            float4* p = (float4*)(bp + bi * 16);
            if (add) { float4 o = *p; w.x += o.x; w.y += o.y; w.z += o.z; w.w += o.w; }
            *p = w;
        }
    };
    if (q < 2) { pwrite(T1, q, acc1, false); pwrite(T2, q, acc2, false); }
    __syncthreads();
    if (q >= 2) { pwrite(T1, q - 2, acc1, true); pwrite(T2, q - 2, acc2, true); }
    __syncthreads();

    // ---- phase C: thread tid = pool index; sum 2 slots, pool8, rowmax, normalize ----
    {
        const int T  = tid >> 7;
        const int j2 = (tid >> 2) & 31;
        const int rq = tid & 3;
        const unsigned char* b0 = smem + (T * 2) * 4096 + j2 * 128;
        const int biA = (2 * rq)     ^ (j2 & 7);
        const int biB = (2 * rq + 1) ^ (j2 & 7);
        float4 s0a = *(const float4*)(b0 + biA * 16);
        float4 s0b = *(const float4*)(b0 + biB * 16);
        float4 s1a = *(const float4*)(b0 + 4096 + biA * 16);
        float4 s1b = *(const float4*)(b0 + 4096 + biB * 16);
        float v0 = s0a.x + s1a.x, v1 = s0a.y + s1a.y, v2 = s0a.z + s1a.z, v3 = s0a.w + s1a.w;
        float v4 = s0b.x + s1b.x, v5 = s0b.y + s1b.y, v6 = s0b.z + s1b.z, v7 = s0b.w + s1b.w;
        float m = fmaxf(fmaxf(fmaxf(v0, v1), fmaxf(v2, v3)), fmaxf(fmaxf(v4, v5), fmaxf(v6, v7)));

        float mx = m;
        for (int off = 32; off > 0; off >>= 1) mx = fmaxf(mx, __shfl_xor(mx, off));
        if (lane == 0) red[wv] = mx;
        __syncthreads();
        float pmax = red[0];
        #pragma unroll
        for (int k = 1; k < 16; ++k) pmax = fmaxf(pmax, red[k]);
        ws[(size_t)row * 1024 + tid] = m * (1.0f / pmax);
    }
}

// K2: MLP, one row per block; split-K per wave, 8 neurons in flight (round-6 verified, unchanged)
__global__ __launch_bounds__(512)
void mlp_kernel(const float* __restrict__ ws,
                const float* __restrict__ W1, const float* __restrict__ b1,
                const float* __restrict__ W2, const float* __restrict__ b2,
                const float* __restrict__ W3, const float* __restrict__ b3,
                float* __restrict__ out)
{
    __shared__ __align__(16) float nrow[1024];
    __shared__ __align__(16) float h1[512];
    __shared__ __align__(16) float h2[256];
    const int tid  = threadIdx.x;
    const int lane = tid & 63;
    const int wv   = tid >> 6;
    const int row  = blockIdx.x;

    if (tid < 256)
        ((float4*)nrow)[tid] = ((const float4*)(ws + (size_t)row * 1024))[tid];
    __syncthreads();

    {
        const float4* n4 = (const float4*)nrow;
        float4 nv0 = n4[lane], nv1 = n4[lane + 64], nv2 = n4[lane + 128], nv3 = n4[lane + 192];
        for (int n0 = 0; n0 < 64; n0 += 8) {
            const int nb = wv * 64 + n0;
            float s[8];
            #pragma unroll
            for (int u = 0; u < 8; ++u) {
                const float4* wr = (const float4*)(W1 + (size_t)(nb + u) * 1024);
                float4 w0 = wr[lane], w1 = wr[lane + 64], w2 = wr[lane + 128], w3 = wr[lane + 192];
                float t0 = w0.x*nv0.x + w0.y*nv0.y + w0.z*nv0.z + w0.w*nv0.w;
                float t1 = w1.x*nv1.x + w1.y*nv1.y + w1.z*nv1.z + w1.w*nv1.w;
                float t2 = w2.x*nv2.x + w2.y*nv2.y + w2.z*nv2.z + w2.w*nv2.w;
                float t3 = w3.x*nv3.x + w3.y*nv3.y + w3.z*nv3.z + w3.w*nv3.w;
                s[u] = (t0 + t1) + (t2 + t3);
            }
            #pragma unroll
            for (int off = 32; off > 0; off >>= 1) {
                #pragma unroll
                for (int u = 0; u < 8; ++u) s[u] += __shfl_xor(s[u], off);
            }
            if (lane == 0) {
                #pragma unroll
                for (int u = 0; u < 8; ++u) h1[nb + u] = lrelu(s[u] + b1[nb + u]);
            }
        }
    }
    __syncthreads();

    {
        const float4* a4 = (const float4*)h1;
        float4 av0 = a4[lane], av1 = a4[lane + 64];
        for (int n0 = 0; n0 < 32; n0 += 8) {
            const int nb = wv * 32 + n0;
            float s[8];
            #pragma unroll
            for (int u = 0; u < 8; ++u) {
                const float4* wr = (const float4*)(W2 + (size_t)(nb + u) * 512);
                float4 w0 = wr[lane], w1 = wr[lane + 64];
                float t0 = w0.x*av0.x + w0.y*av0.y + w0.z*av0.z + w0.w*av0.w;
                float t1 = w1.x*av1.x + w1.y*av1.y + w1.z*av1.z + w1.w*av1.w;
                s[u] = t0 + t1;
            }
            #pragma unroll
            for (int off = 32; off > 0; off >>= 1) {
                #pragma unroll
                for (int u = 0; u < 8; ++u) s[u] += __shfl_xor(s[u], off);
            }
            if (lane == 0) {
                #pragma unroll
                for (int u = 0; u < 8; ++u) h2[nb + u] = lrelu(s[u] + b2[nb + u]);
            }
        }
    }
    __syncthreads();

    if (wv < 4) {
        const float4 w = ((const float4*)(W3 + wv * 256))[lane];
        const float4 a = ((const float4*)h2)[lane];
        float s = w.x*a.x + w.y*a.y + w.z*a.z + w.w*a.w;
        for (int off = 32; off > 0; off >>= 1) s += __shfl_xor(s, off);
        if (lane == 0) out[row * 4 + wv] = s + b3[wv];
    }
}

extern "C" void kernel_launch(void* const* d_in, const int* in_sizes, int n_in,
                              void* d_out, int out_size, void* d_ws, size_t ws_size,
                              hipStream_t stream)
{
    const float* x  = (const float*)d_in[0];
    const float* W1 = (const float*)d_in[1];
    const float* b1 = (const float*)d_in[2];
    const float* W2 = (const float*)d_in[3];
    const float* b2 = (const float*)d_in[4];
    const float* W3 = (const float*)d_in[5];
    const float* b3 = (const float*)d_in[6];
    float* outp = (float*)d_out;
    float* wsn  = (float*)d_ws;   // 256*1024 fp32 normalized features

    hipLaunchKernelGGL(acf_kernel, dim3(256), dim3(1024), 0, stream, x, wsn);
    hipLaunchKernelGGL(mlp_kernel, dim3(256), dim3(512), 0, stream,
                       wsn, W1, b1, W2, b2, W3, b3, outp);
}

// Round 8
// 63.135 us; speedup vs baseline: 15.2215x; 1.1798x over previous
//
#include <hip/hip_runtime.h>

typedef __attribute__((ext_vector_type(8))) short bf16x8;
typedef __attribute__((ext_vector_type(16))) float f32x16;

#define LN 8192
#define SA_ROWB 4240          // bytes/shifted-copy row; 4240/16=265 ≡ 1 (mod 8) → bank spread
#define SB_OFF  33920         // B buffer starts after 8 A-rows (8*4240)
#define SMEM_BYTES 65536

__device__ __forceinline__ unsigned short f2bf(float f) {
    unsigned int u = __float_as_uint(f);
    u += 0x7fffu + ((u >> 16) & 1u);
    return (unsigned short)(u >> 16);
}
__device__ __forceinline__ float lrelu(float v) { return v > 0.f ? v : 0.01f * v; }
__device__ __forceinline__ float gldx(const float* p, int i) { return (i >= 0 && i < LN) ? p[i] : 0.f; }

// K1: ACF via 32x32x16 bf16 MFMA, A shared across tile pair (T1=p, T2=7-p).
// Pair's work list mq-major (dual item while mq<s2), 4 equal 144-MFMA slices.
__global__ __launch_bounds__(1024)
void acf_kernel(const float* __restrict__ x, float* __restrict__ ws)
{
    __shared__ __align__(16) unsigned char smem[SMEM_BYTES];
    __shared__ float red[16];

    const int tid  = threadIdx.x;
    const int row  = blockIdx.x;
    const int lane = tid & 63;
    const int wv   = tid >> 6;
    const float* xr = x + (size_t)row * LN;

    // lane constants (identical to round 7)
    const int jj = lane & 31;
    const int gp = lane >> 5;
    const int dd = lane & 7;
    const int hh = (lane >> 3) & 3;
    const int aoff_lane = dd * SA_ROWB + 64 + 16 * gp - 16 * hh;

    // wave job: pair p, slice q of the pair's combined (mq,T) item list
    const int q  = wv & 3;
    const int p  = wv >> 2;
    const int T1 = p;
    const int T2 = 7 - p;
    const int s1 = 512 - 64 * p;     // T1 mq-count
    const int s2 = 64 + 64 * p;      // T2 mq-count (<= s1)
    const int i0 = 144 * q;
    const int i1 = i0 + 144;
    const int mq0 = (i0 <= 2 * s2) ? (72 * q)       : (i0 - s2);
    const int mqE = (i1 <= 2 * s2) ? (72 * (q + 1)) : (i1 - s2);

    // ---- stage B: padded bf16 v (9248 elems), 16B-slot XOR swizzle s^((s>>3)&7) ----
    for (int s = tid; s < 1156; s += 1024) {
        const int e0 = s * 8;
        float4 fa, fb;
        if (e0 + 7 < LN) {
            fa = *(const float4*)(xr + e0);
            fb = *(const float4*)(xr + e0 + 4);
        } else {
            fa = make_float4(gldx(xr,e0),   gldx(xr,e0+1), gldx(xr,e0+2), gldx(xr,e0+3));
            fb = make_float4(gldx(xr,e0+4), gldx(xr,e0+5), gldx(xr,e0+6), gldx(xr,e0+7));
        }
        uint4 pk;
        pk.x = (unsigned)f2bf(fa.x) | ((unsigned)f2bf(fa.y) << 16);
        pk.y = (unsigned)f2bf(fa.z) | ((unsigned)f2bf(fa.w) << 16);
        pk.z = (unsigned)f2bf(fb.x) | ((unsigned)f2bf(fb.y) << 16);
        pk.w = (unsigned)f2bf(fb.z) | ((unsigned)f2bf(fb.w) << 16);
        const int ph = s ^ ((s >> 3) & 7);
        *(uint4*)(smem + SB_OFF + ph * 16) = pk;
    }

    f32x16 acc1 = {}, acc2 = {};

    for (int ch = 0; ch < 4; ++ch) {
        const int tc = ch << 11;
        __syncthreads();
        // ---- stage A: copy_d[p4] = v[tc + p4 - 32 - d] (identical to round 7) ----
        if (tid < 528) {
            const int base = tc + 4 * tid - 40;
            float4 fa, fb, fc;
            if (base >= 0 && base + 11 < LN) {
                fa = *(const float4*)(xr + base);
                fb = *(const float4*)(xr + base + 4);
                fc = *(const float4*)(xr + base + 8);
            } else {
                fa = make_float4(gldx(xr,base),   gldx(xr,base+1), gldx(xr,base+2),  gldx(xr,base+3));
                fb = make_float4(gldx(xr,base+4), gldx(xr,base+5), gldx(xr,base+6),  gldx(xr,base+7));
                fc = make_float4(gldx(xr,base+8), gldx(xr,base+9), gldx(xr,base+10), gldx(xr,base+11));
            }
            unsigned short us[12];
            us[0]=f2bf(fa.x); us[1]=f2bf(fa.y); us[2]=f2bf(fa.z);  us[3]=f2bf(fa.w);
            us[4]=f2bf(fb.x); us[5]=f2bf(fb.y); us[6]=f2bf(fb.z);  us[7]=f2bf(fb.w);
            us[8]=f2bf(fc.x); us[9]=f2bf(fc.y); us[10]=f2bf(fc.z); us[11]=f2bf(fc.w);
            #pragma unroll
            for (int d = 0; d < 8; ++d) {
                unsigned long long pk = (unsigned long long)us[8-d]
                                      | ((unsigned long long)us[9-d]  << 16)
                                      | ((unsigned long long)us[10-d] << 32)
                                      | ((unsigned long long)us[11-d] << 48);
                *(unsigned long long*)(smem + d * SA_ROWB + 8 * tid) = pk;
            }
        }
        __syncthreads();

        const int cb = ch * 128;
        int m0 = mq0 > cb ? mq0 : cb;
        int mE = mqE < cb + 128 ? mqE : cb + 128;
        if (m0 < mE) {
            int mD = mE < s2 ? mE : s2;          // dual-part end
            if (mD < m0) mD = m0;
            const unsigned char* ap = smem + aoff_lane + 32 * (m0 - cb);
            int S1 = 128 * T1 + 2 * m0 + 4 * jj + gp;
            int S2 = 128 * T2 + 2 * m0 + 4 * jj + gp;
            // dual: A shared between both tiles (bounds mult-of-8 -> exact unroll 4)
            for (int mq = m0; mq < mD; mq += 4) {
                bf16x8 A[4], B1[4], B2[4];
                #pragma unroll
                for (int u = 0; u < 4; ++u) {
                    A[u] = *(const bf16x8*)(ap + 32 * u);
                    const int sa = S1 + 2 * u, sb = S2 + 2 * u;
                    B1[u] = *(const bf16x8*)(smem + SB_OFF + ((sa ^ ((sa >> 3) & 7)) << 4));
                    B2[u] = *(const bf16x8*)(smem + SB_OFF + ((sb ^ ((sb >> 3) & 7)) << 4));
                }
                #pragma unroll
                for (int u = 0; u < 4; ++u) {
                    acc1 = __builtin_amdgcn_mfma_f32_32x32x16_bf16(A[u], B1[u], acc1, 0, 0, 0);
                    acc2 = __builtin_amdgcn_mfma_f32_32x32x16_bf16(A[u], B2[u], acc2, 0, 0, 0);
                }
                ap += 128; S1 += 8; S2 += 8;
            }
            // single: T1 only
            for (int mq = mD; mq < mE; mq += 4) {
                bf16x8 A[4], B1[4];
                #pragma unroll
                for (int u = 0; u < 4; ++u) {
                    A[u] = *(const bf16x8*)(ap + 32 * u);
                    const int sa = S1 + 2 * u;
                    B1[u] = *(const bf16x8*)(smem + SB_OFF + ((sa ^ ((sa >> 3) & 7)) << 4));
                }
                #pragma unroll
                for (int u = 0; u < 4; ++u)
                    acc1 = __builtin_amdgcn_mfma_f32_32x32x16_bf16(A[u], B1[u], acc1, 0, 0, 0);
                ap += 128; S1 += 8;
            }
        }
    }

    __syncthreads();   // all MFMA reads done; overlay staging with partial buffer

    // partial buffer: [T][s][j(32)][i(32 f32, 16B-blocks XOR-swizzled by j&7)] (identical)
    auto pwrite = [&](int T, int s, const f32x16& acc, bool add) {
        unsigned char* bp = smem + (T * 2 + s) * 4096 + jj * 128;
        #pragma unroll
        for (int rq = 0; rq < 4; ++rq) {
            const int bi = (2 * rq + gp) ^ (jj & 7);
            float4 w = make_float4(acc[4*rq], acc[4*rq+1], acc[4*rq+2], acc[4*rq+3]);
            float4* pp = (float4*)(bp + bi * 16);
            if (add) { float4 o = *pp; w.x += o.x; w.y += o.y; w.z += o.z; w.w += o.w; }
            *pp = w;
        }
    };
    if (q < 2) { pwrite(T1, q, acc1, false); pwrite(T2, q, acc2, false); }
    __syncthreads();
    if (q >= 2) { pwrite(T1, q - 2, acc1, true); pwrite(T2, q - 2, acc2, true); }
    __syncthreads();

    // ---- phase C: sum 2 slots, pool8, rowmax, normalize (identical) ----
    {
        const int T  = tid >> 7;
        const int j2 = (tid >> 2) & 31;
        const int rq = tid & 3;
        const unsigned char* b0 = smem + (T * 2) * 4096 + j2 * 128;
        const int biA = (2 * rq)     ^ (j2 & 7);
        const int biB = (2 * rq + 1) ^ (j2 & 7);
        float4 s0a = *(const float4*)(b0 + biA * 16);
        float4 s0b = *(const float4*)(b0 + biB * 16);
        float4 s1a = *(const float4*)(b0 + 4096 + biA * 16);
        float4 s1b = *(const float4*)(b0 + 4096 + biB * 16);
        float v0 = s0a.x + s1a.x, v1 = s0a.y + s1a.y, v2 = s0a.z + s1a.z, v3 = s0a.w + s1a.w;
        float v4 = s0b.x + s1b.x, v5 = s0b.y + s1b.y, v6 = s0b.z + s1b.z, v7 = s0b.w + s1b.w;
        float m = fmaxf(fmaxf(fmaxf(v0, v1), fmaxf(v2, v3)), fmaxf(fmaxf(v4, v5), fmaxf(v6, v7)));

        float mx = m;
        for (int off = 32; off > 0; off >>= 1) mx = fmaxf(mx, __shfl_xor(mx, off));
        if (lane == 0) red[wv] = mx;
        __syncthreads();
        float pmax = red[0];
        #pragma unroll
        for (int k = 1; k < 16; ++k) pmax = fmaxf(pmax, red[k]);
        ws[(size_t)row * 1024 + tid] = m * (1.0f / pmax);
    }
}

// K2a: layer 1 neuron-tiled GEMM. 256 blocks = 32 row-groups x 8 neuron-groups.
// Per-CU bytes: 64 neurons x 4KB + 8 rows x 4KB = 288KB (vs 2.6MB row-blocked).
__global__ __launch_bounds__(512)
void mlp1_kernel(const float* __restrict__ ws, const float* __restrict__ W1,
                 const float* __restrict__ b1, float* __restrict__ h1g)
{
    __shared__ __align__(16) float arow[8 * 1024];
    const int tid  = threadIdx.x;
    const int lane = tid & 63;
    const int wv   = tid >> 6;
    const int bn   = blockIdx.x & 7;
    const int rb   = blockIdx.x >> 3;

    const float4* src = (const float4*)(ws + (size_t)rb * 8192);
    float4* a4 = (float4*)arow;
    for (int i = tid; i < 2048; i += 512) a4[i] = src[i];
    __syncthreads();

    const int n0 = bn * 64 + wv * 8;
    float acc[8][8];   // [neuron u][row r], fully static indexing
    #pragma unroll
    for (int u = 0; u < 8; ++u)
        #pragma unroll
        for (int r = 0; r < 8; ++r) acc[u][r] = 0.f;

    #pragma unroll
    for (int qq = 0; qq < 4; ++qq) {
        const int kq = lane + 64 * qq;
        float4 av[8];
        #pragma unroll
        for (int r = 0; r < 8; ++r) av[r] = a4[r * 256 + kq];
        #pragma unroll
        for (int u = 0; u < 8; ++u) {
            float4 w = ((const float4*)(W1 + (size_t)(n0 + u) * 1024))[kq];
            #pragma unroll
            for (int r = 0; r < 8; ++r)
                acc[u][r] += w.x*av[r].x + w.y*av[r].y + w.z*av[r].z + w.w*av[r].w;
        }
    }
    #pragma unroll
    for (int off = 32; off > 0; off >>= 1)
        #pragma unroll
        for (int u = 0; u < 8; ++u)
            #pragma unroll
            for (int r = 0; r < 8; ++r) acc[u][r] += __shfl_xor(acc[u][r], off);

    if (lane == 0) {
        #pragma unroll
        for (int u = 0; u < 8; ++u) {
            const float bb = b1[n0 + u];
            #pragma unroll
            for (int r = 0; r < 8; ++r)
                h1g[(size_t)(rb * 8 + r) * 512 + n0 + u] = lrelu(acc[u][r] + bb);
        }
    }
}

// K2b: layers 2+3 row-per-block (round-6 verified structure).
__global__ __launch_bounds__(512)
void mlp23_kernel(const float* __restrict__ h1g,
                  const float* __restrict__ W2, const float* __restrict__ b2,
                  const float* __restrict__ W3, const float* __restrict__ b3,
                  float* __restrict__ out)
{
    __shared__ __align__(16) float h1s[512];
    __shared__ __align__(16) float h2[256];
    const int tid  = threadIdx.x;
    const int lane = tid & 63;
    const int wv   = tid >> 6;
    const int row  = blockIdx.x;

    if (tid < 128) ((float4*)h1s)[tid] = ((const float4*)(h1g + (size_t)row * 512))[tid];
    __syncthreads();

    {
        const float4* a4 = (const float4*)h1s;
        float4 av0 = a4[lane], av1 = a4[lane + 64];
        for (int n0 = 0; n0 < 32; n0 += 8) {
            const int nb = wv * 32 + n0;
            float s[8];
            #pragma unroll
            for (int u = 0; u < 8; ++u) {
                const float4* wr = (const float4*)(W2 + (size_t)(nb + u) * 512);
                float4 w0 = wr[lane], w1 = wr[lane + 64];
                float t0 = w0.x*av0.x + w0.y*av0.y + w0.z*av0.z + w0.w*av0.w;
                float t1 = w1.x*av1.x + w1.y*av1.y + w1.z*av1.z + w1.w*av1.w;
                s[u] = t0 + t1;
            }
            #pragma unroll
            for (int off = 32; off > 0; off >>= 1) {
                #pragma unroll
                for (int u = 0; u < 8; ++u) s[u] += __shfl_xor(s[u], off);
            }
            if (lane == 0) {
                #pragma unroll
                for (int u = 0; u < 8; ++u) h2[nb + u] = lrelu(s[u] + b2[nb + u]);
            }
        }
    }
    __syncthreads();

    if (wv < 4) {
        const float4 w = ((const float4*)(W3 + wv * 256))[lane];
        const float4 a = ((const float4*)h2)[lane];
        float s = w.x*a.x + w.y*a.y + w.z*a.z + w.w*a.w;
        for (int off = 32; off > 0; off >>= 1) s += __shfl_xor(s, off);
        if (lane == 0) out[row * 4 + wv] = s + b3[wv];
    }
}

extern "C" void kernel_launch(void* const* d_in, const int* in_sizes, int n_in,
                              void* d_out, int out_size, void* d_ws, size_t ws_size,
                              hipStream_t stream)
{
    const float* x  = (const float*)d_in[0];
    const float* W1 = (const float*)d_in[1];
    const float* b1 = (const float*)d_in[2];
    const float* W2 = (const float*)d_in[3];
    const float* b2 = (const float*)d_in[4];
    const float* W3 = (const float*)d_in[5];
    const float* b3 = (const float*)d_in[6];
    float* outp = (float*)d_out;
    float* wsn  = (float*)d_ws;                  // [0, 1MB): normalized features
    float* h1g  = wsn + 256 * 1024;              // [1MB, 1.5MB): h1 activations

    hipLaunchKernelGGL(acf_kernel,   dim3(256), dim3(1024), 0, stream, x, wsn);
    hipLaunchKernelGGL(mlp1_kernel,  dim3(256), dim3(512),  0, stream, wsn, W1, b1, h1g);
    hipLaunchKernelGGL(mlp23_kernel, dim3(256), dim3(512),  0, stream, h1g, W2, b2, W3, b3, outp);
}